// Round 11
// baseline (1287.087 us; speedup 1.0000x reference)
//
#include <hip/hip_runtime.h>
#include <math.h>

// Problem constants
#define B_SZ   1024
#define H_SZ   512
#define E_SZ   100
#define L_SZ   128
#define KX     128          // embedding width padded 100 -> 128
#define VOCAB  50000

typedef _Float16 f16x8  __attribute__((ext_vector_type(8)));
typedef float    f32x4  __attribute__((ext_vector_type(4)));
typedef float    f32x16 __attribute__((ext_vector_type(16)));

#define MFMA16(a, b, c) __builtin_amdgcn_mfma_f32_16x16x32_f16((a), (b), (c), 0, 0, 0)
#define MFMA32(a, b, c) __builtin_amdgcn_mfma_f32_32x32x16_f16((a), (b), (c), 0, 0, 0)

__device__ __forceinline__ float fast_sigmoid(float x) {
    return __builtin_amdgcn_rcpf(1.0f + __expf(-x));
}
__device__ __forceinline__ float fast_tanh(float x) {
    return 1.0f - 2.0f * __builtin_amdgcn_rcpf(1.0f + __expf(2.0f * x));
}

// ---------------------------------------------------------------------------
// Convert embedding tables to fp16, pad rows 100 -> 128.
// ---------------------------------------------------------------------------
__global__ __launch_bounds__(256) void prep_emb_kernel(
    _Float16* __restrict__ ef_c, const float* __restrict__ e_c,
    _Float16* __restrict__ ef_r, const float* __restrict__ e_r)
{
    const int PER = VOCAB * KX;                // 6,400,000
    int idx = blockIdx.x * 256 + threadIdx.x;
    if (idx >= 2 * PER) return;
    const int gru = idx >= PER;
    const int local = gru ? idx - PER : idx;
    const int v = local >> 7;                  // /128
    const int e = local & 127;
    const float* src = gru ? e_r : e_c;
    _Float16* dst = gru ? ef_r : ef_c;
    dst[local] = (_Float16)(e < E_SZ ? src[v * E_SZ + e] : 0.0f);
}

// ---------------------------------------------------------------------------
// Persistent GRU kernel: all 128 time steps in ONE launch.
//
// R21: 32x32 MFMA (layout PROVEN by R20's pass) at 8 waves / 2-per-SIMD
// (R14's proven TLP) via K-SPLIT wave pairs:
//   * Wave (rg = wave>>1, wk = wave&1): rows mB+rg*32..+31, K-half wk
//     (h-cols [wk*256,+256), x-cols [wk*64,+64)). Per wave 60 MFMA32 +
//     60 B-frag reads + 16 h-loads. Per CU: 480 B-reads (HALF of R14's
//     960 -> -5.7kcyc LDS pipe), 480 MFMA32 (same FLOPs, -0.9kcyc pipe).
//   * Block h-read stays 128KB/step -> 16 readers/row (R15/R18/R19 lesson:
//     NEVER add h readers).
//   * Partial-acc reduction: two-phase f32 exchange via 32KB LDS buffer
//     (float2 [jjp][rg][lane]: lanes hit 2-way bank alias = free, m136),
//     3 extra __syncthreads -- ALL intra-block, zero new spin surface.
//     wk=0 wave sums partials + runs the R20-verbatim epilogue/store.
//   * Inter-block barrier, role claim, staging: R14/R20 VERBATIM.
//   * R20's regression isolated the TLP loss (1 wave/SIMD), not the shape:
//     this keeps the halved LDS AND the 2-wave/SIMD latency hiding.
// ---------------------------------------------------------------------------
struct GruArgs {
    const float* Whh[2];
    const float* Wih[2];
    const float* bih[2];
    const float* bhh[2];
    const _Float16* emb[2];
    const int* idx[2];
    _Float16* hA;          // [2][1024][512] ping (h0 = 0, final h)
    _Float16* hB;          // [2][1024][512] pong
    unsigned int* bars;    // 16 groups, stride 32 uints (128B apart)
    unsigned int* claim;   // 8 per-XCD slot counters
};

__global__ __launch_bounds__(512, 2) void gru_persistent(GruArgs args)
{
    // ---- XCD discovery + role claim (once per block) ----
    __shared__ int role_s;
    if (threadIdx.x == 0) {
        unsigned xcd;
        asm volatile("s_getreg_b32 %0, hwreg(HW_REG_XCC_ID)" : "=s"(xcd));
        xcd &= 7u;
        unsigned slot = atomicAdd(&args.claim[xcd], 1u);   // device-scope
        role_s = (int)(xcd * 32u + slot);
    }
    __syncthreads();
    const int role = role_s;
    const int grp  = role >> 4;    // 0..15  (2 groups per XCD, XCD-local)
    const int ut   = role & 15;    // u-slice within group
    const int gru  = grp >> 3;
    const int mt   = grp & 7;

    const float* __restrict__ Whh = args.Whh[gru];
    const float* __restrict__ Wih = args.Wih[gru];
    const float* __restrict__ bih = args.bih[gru];
    const float* __restrict__ bhh = args.bhh[gru];
    const _Float16* __restrict__ embf = args.emb[gru];
    const int* __restrict__ idx = args.idx[gru];

    const int u0 = ut * 32;        // block's hidden-unit base (32 units)
    const int mB = mt * 128;       // block's batch-row base (128 rows)

    // Fragment-order weight store: [kc=40][g=3][lane=64] x f16x8 = 122,880B
    __shared__ _Float16 Wl[7680 * 8];
    // K-split partial-acc exchange: [16 float2-slots][4 rg][64 lanes] = 32KB
    __shared__ float2 xb[16][4][64];

    // ---- stage weights fp32 -> fp16 fragments (once; R20 verbatim) ----
    // Fragment (kc,g,lane): lane = col(0..31) + 32*kh; holds
    // W[g*512 + u0 + col][kc*16 + kh*8 + j], j=0..7.
    for (int f = threadIdx.x; f < 7680; f += 512) {
        const int ln  = f & 63;
        const int q   = f >> 6;          // 0..119
        const int kc  = q / 3;           // 0..39
        const int g   = q - kc * 3;
        const int col = ln & 31;
        const int kh  = ln >> 5;
        const int row = g * H_SZ + u0 + col;
        _Float16 tmp[8];
        if (kc < 32) {
            const float* src = Whh + (size_t)row * H_SZ + kc * 16 + kh * 8;
#pragma unroll
            for (int j = 0; j < 8; ++j) tmp[j] = (_Float16)src[j];
        } else {
            const int e = (kc - 32) * 16 + kh * 8;
#pragma unroll
            for (int j = 0; j < 8; ++j)
                tmp[j] = (_Float16)((e + j < E_SZ) ? Wih[(size_t)row * E_SZ + e + j]
                                                   : 0.0f);
        }
        *(f16x8*)&Wl[(size_t)f * 8] = *(const f16x8*)tmp;
    }
    __syncthreads();

    const int lane = threadIdx.x & 63;
    const int wave = threadIdx.x >> 6;   // 0..7
    const int rg   = wave >> 1;          // row-group 0..3 (32 rows each)
    const int wk   = wave & 1;           // K-half
    const int lr   = lane & 31;          // fragment row / output col
    const int kh2  = lane >> 5;          // k-subhalf within fragment (0,1)
    const int mw   = mB + rg * 32;       // wave's 32-row batch base

    // per-lane fragment base: reads become base + const-offset
    const _Float16* Wbase = Wl + (size_t)lane * 8;
#define WFRAG(kc, g) \
    (*(const f16x8*)(Wbase + (size_t)(((kc) * 3 + (g)) * 64) * 8))

    // bias preload: this thread's single u column
    const int ucol = u0 + lr;
    const float bir  = bih[ucol]            + bhh[ucol];
    const float biz  = bih[H_SZ + ucol]     + bhh[H_SZ + ucol];
    const float binn = bih[2 * H_SZ + ucol];
    const float bhn  = bhh[2 * H_SZ + ucol];

    _Float16* hbuf0 = args.hA + (size_t)gru * B_SZ * H_SZ;
    _Float16* hbuf1 = args.hB + (size_t)gru * B_SZ * H_SZ;
    unsigned int* bar = args.bars + grp * 32;

    // h_prev at this thread's own output coordinates (wk==0 waves only).
    float hreg[16] = {};   // [reg]

    // ---- emb software pipeline state (all compiler-managed loads) ----
    // er[i]: A fragment for x-kc = 32 + wk*4 + i:
    //        emb[iv][wk*64 + i*16 + kh2*8 + j]
    f16x8 er[4];
    int ivn;
    {
        const int iv_c = idx[(mw + lr) * L_SZ + (L_SZ - 1)];   // step 0
        const _Float16* e0 = embf + (size_t)iv_c * KX + wk * 64 + kh2 * 8;
#pragma unroll
        for (int i = 0; i < 4; ++i)
            er[i] = *(const f16x8*)(e0 + i * 16);
        ivn = idx[(mw + lr) * L_SZ + (L_SZ - 2)];              // step 1
    }

#pragma unroll 1
    for (int step = 0; step < L_SZ; ++step) {
        const _Float16* __restrict__ hin = (step & 1) ? hbuf1 : hbuf0;
        _Float16* __restrict__ hout      = (step & 1) ? hbuf0 : hbuf1;

        f32x16 accr  = {0.f,0.f,0.f,0.f,0.f,0.f,0.f,0.f,0.f,0.f,0.f,0.f,0.f,0.f,0.f,0.f};
        f32x16 accz  = {0.f,0.f,0.f,0.f,0.f,0.f,0.f,0.f,0.f,0.f,0.f,0.f,0.f,0.f,0.f,0.f};
        f32x16 acchn = {0.f,0.f,0.f,0.f,0.f,0.f,0.f,0.f,0.f,0.f,0.f,0.f,0.f,0.f,0.f,0.f};
        f32x16 accin = {0.f,0.f,0.f,0.f,0.f,0.f,0.f,0.f,0.f,0.f,0.f,0.f,0.f,0.f,0.f,0.f};

        // ---- x-part: this wave's 4 x-kc fragments (12 MFMA) ----
#pragma unroll
        for (int i = 0; i < 4; ++i) {
            const int kc = 32 + wk * 4 + i;
            accr  = MFMA32(er[i], WFRAG(kc, 0), accr);
            accz  = MFMA32(er[i], WFRAG(kc, 1), accz);
            accin = MFMA32(er[i], WFRAG(kc, 2), accin);
        }

        // ---- wait for h(step): R14's PROVEN LLC barrier ----
        if (step > 0) {
            if (threadIdx.x == 0) {
                const unsigned tgt = 16u * (unsigned)step;
                while (__hip_atomic_load(bar, __ATOMIC_RELAXED,
                                         __HIP_MEMORY_SCOPE_AGENT) < tgt)
                    __builtin_amdgcn_s_sleep(1);
            }
            __syncthreads();
        }

        // ---- h-part A-slab: this wave's K-half (256 cols) as 16 fragments
        // in ONE asm batch (proven form: internal vmcnt(0), sc0). ----
        const _Float16* hrow0 = hin + (mw + lr) * H_SZ + wk * 256 + kh2 * 8;
        f16x8 a0h[16];
        asm volatile(
            "global_load_dwordx4 %0,  %16, off sc0\n\t"
            "global_load_dwordx4 %1,  %16, off offset:32 sc0\n\t"
            "global_load_dwordx4 %2,  %16, off offset:64 sc0\n\t"
            "global_load_dwordx4 %3,  %16, off offset:96 sc0\n\t"
            "global_load_dwordx4 %4,  %16, off offset:128 sc0\n\t"
            "global_load_dwordx4 %5,  %16, off offset:160 sc0\n\t"
            "global_load_dwordx4 %6,  %16, off offset:192 sc0\n\t"
            "global_load_dwordx4 %7,  %16, off offset:224 sc0\n\t"
            "global_load_dwordx4 %8,  %16, off offset:256 sc0\n\t"
            "global_load_dwordx4 %9,  %16, off offset:288 sc0\n\t"
            "global_load_dwordx4 %10, %16, off offset:320 sc0\n\t"
            "global_load_dwordx4 %11, %16, off offset:352 sc0\n\t"
            "global_load_dwordx4 %12, %16, off offset:384 sc0\n\t"
            "global_load_dwordx4 %13, %16, off offset:416 sc0\n\t"
            "global_load_dwordx4 %14, %16, off offset:448 sc0\n\t"
            "global_load_dwordx4 %15, %16, off offset:480 sc0\n\t"
            "s_waitcnt vmcnt(0)"
            : "=&v"(a0h[0]),  "=&v"(a0h[1]),  "=&v"(a0h[2]),  "=&v"(a0h[3]),
              "=&v"(a0h[4]),  "=&v"(a0h[5]),  "=&v"(a0h[6]),  "=&v"(a0h[7]),
              "=&v"(a0h[8]),  "=&v"(a0h[9]),  "=&v"(a0h[10]), "=&v"(a0h[11]),
              "=&v"(a0h[12]), "=&v"(a0h[13]), "=&v"(a0h[14]), "=&v"(a0h[15])
            : "v"(hrow0)
            : "memory");

        // ---- emb prefetch for step+1 (compiler-managed) ----
        {
            const _Float16* erow = embf + (size_t)ivn * KX + wk * 64 + kh2 * 8;
#pragma unroll
            for (int i = 0; i < 4; ++i)
                er[i] = *(const f16x8*)(erow + i * 16);
            int lc = L_SZ - 3 - step;          // lcol for step+2
            if (lc < 0) lc = 0;                // tail: valid junk, unused
            ivn = idx[(mw + lr) * L_SZ + lc];
        }

        // ---- h-part MFMAs: this wave's 16 kc x 3 ----
#pragma unroll
        for (int j = 0; j < 16; ++j) {
            const int kc = wk * 16 + j;
            accr  = MFMA32(a0h[j], WFRAG(kc, 0), accr);
            accz  = MFMA32(a0h[j], WFRAG(kc, 1), accz);
            acchn = MFMA32(a0h[j], WFRAG(kc, 2), acchn);
        }

        // ---- K-split reduction: two-phase f32 exchange (intra-block) ----
        // Lane coords identical across the pair (same C/D mapping), so
        // lane-ln partials add elementwise.
        if (wk == 1) {
#pragma unroll
            for (int p = 0; p < 8; ++p) {
                xb[p][rg][lane]     = make_float2(accr[2*p], accr[2*p+1]);
                xb[8 + p][rg][lane] = make_float2(accz[2*p], accz[2*p+1]);
            }
        }
        __syncthreads();
        if (wk == 0) {
#pragma unroll
            for (int p = 0; p < 8; ++p) {
                float2 a = xb[p][rg][lane];
                float2 b = xb[8 + p][rg][lane];
                accr[2*p] += a.x;  accr[2*p+1] += a.y;
                accz[2*p] += b.x;  accz[2*p+1] += b.y;
            }
        }
        __syncthreads();
        if (wk == 1) {
#pragma unroll
            for (int p = 0; p < 8; ++p) {
                xb[p][rg][lane]     = make_float2(acchn[2*p], acchn[2*p+1]);
                xb[8 + p][rg][lane] = make_float2(accin[2*p], accin[2*p+1]);
            }
        }
        __syncthreads();

        // ---- epilogue (wk==0 waves): R20-verbatim gates + store ----
        // C/D layout (m101): col = lane&31, row = (reg&3)+8*(reg>>2)+4*kh2
        if (wk == 0) {
#pragma unroll
            for (int r = 0; r < 16; ++r) {
                const int p = r >> 1;
                const float hnp = (r & 1) ? xb[p][rg][lane].y
                                          : xb[p][rg][lane].x;
                const float inp = (r & 1) ? xb[8 + p][rg][lane].y
                                          : xb[8 + p][rg][lane].x;
                const int m = mw + (r & 3) + 8 * (r >> 2) + 4 * kh2;
                const float rg_ = fast_sigmoid(accr[r] + bir);
                const float zg  = fast_sigmoid(accz[r] + biz);
                const float ng  = fast_tanh(accin[r] + inp + binn +
                                            rg_ * (acchn[r] + hnp + bhn));
                float nh = (1.0f - zg) * ng + zg * hreg[r];
                nh = (float)(_Float16)nh;   // bit-match the stored fp16
                hreg[r] = nh;
                hout[m * H_SZ + ucol] = (_Float16)nh;
            }
        }

        // ---- publish (RELAXED agent; stores drained to L2 by syncthreads) ----
        if (step + 1 < L_SZ) {
            __syncthreads();   // drains vmcnt: h stores in L2, emb prefetch
                               // in regs; also closes the xb read window
            if (threadIdx.x == 0) {
                __hip_atomic_fetch_add(bar, 1u, __ATOMIC_RELAXED,
                                       __HIP_MEMORY_SCOPE_AGENT);
            }
        }
    }
    // drain the last step's dead prefetch loads before endpgm
    asm volatile("s_waitcnt vmcnt(0)" ::: "memory");
    // final h (step 127, odd) in hA as dirty local-L2 lines; the dispatch-end
    // release writes them back so the scores kernel sees them.
#undef WFRAG
}

// ---------------------------------------------------------------------------
// scores = hc @ hr^T (fp16 in, fp32 out), MFMA. Block 64x64, wave 32x32.
// ---------------------------------------------------------------------------
__global__ __launch_bounds__(256, 1) void scores_kernel(
    const _Float16* __restrict__ hc, const _Float16* __restrict__ hr,
    float* __restrict__ out)
{
    const int lane = threadIdx.x & 63;
    const int wave = threadIdx.x >> 6;
    const int lr   = lane & 15;
    const int kseg = lane >> 4;
    const int m0 = blockIdx.y * 64 + (wave >> 1) * 32;
    const int n0 = blockIdx.x * 64 + (wave & 1) * 32;

    f32x4 acc[2][2];
#pragma unroll
    for (int i = 0; i < 2; i++)
#pragma unroll
        for (int j = 0; j < 2; j++)
            acc[i][j] = (f32x4){0.f, 0.f, 0.f, 0.f};

#pragma unroll 2
    for (int kc = 0; kc < 16; kc++) {
        const int k0 = kc * 32 + kseg * 8;
        f16x8 a[2], b[2];
#pragma unroll
        for (int mt = 0; mt < 2; mt++)
            a[mt] = *(const f16x8*)(hc + (m0 + mt * 16 + lr) * H_SZ + k0);
#pragma unroll
        for (int nt = 0; nt < 2; nt++)
            b[nt] = *(const f16x8*)(hr + (n0 + nt * 16 + lr) * H_SZ + k0);
#pragma unroll
        for (int mt = 0; mt < 2; mt++)
#pragma unroll
            for (int nt = 0; nt < 2; nt++)
                acc[mt][nt] = MFMA16(a[mt], b[nt], acc[mt][nt]);
    }

#pragma unroll
    for (int mt = 0; mt < 2; mt++)
#pragma unroll
        for (int nt = 0; nt < 2; nt++)
#pragma unroll
            for (int r = 0; r < 4; r++) {
                const int m = m0 + mt * 16 + kseg * 4 + r;
                const int n = n0 + nt * 16 + lr;
                out[m * B_SZ + n] = acc[mt][nt][r];
            }
}

// In-place row softmax on [1024, 1024]; one block per row.
__global__ __launch_bounds__(256) void softmax_kernel(float* __restrict__ out)
{
    const int row = blockIdx.x;
    float* p = out + (size_t)row * B_SZ;
    const int t = threadIdx.x;
    const int wave = t >> 6;
    const int lane = t & 63;

    float4 v = ((const float4*)p)[t];
    float m = fmaxf(fmaxf(v.x, v.y), fmaxf(v.z, v.w));
#pragma unroll
    for (int off = 32; off >= 1; off >>= 1)
        m = fmaxf(m, __shfl_xor(m, off, 64));

    __shared__ float redm[4];
    if (lane == 0) redm[wave] = m;
    __syncthreads();
    m = fmaxf(fmaxf(redm[0], redm[1]), fmaxf(redm[2], redm[3]));

    const float e0 = __expf(v.x - m);
    const float e1 = __expf(v.y - m);
    const float e2 = __expf(v.z - m);
    const float e3 = __expf(v.w - m);
    float s = e0 + e1 + e2 + e3;
#pragma unroll
    for (int off = 32; off >= 1; off >>= 1)
        s += __shfl_xor(s, off, 64);

    __shared__ float reds[4];
    if (lane == 0) reds[wave] = s;
    __syncthreads();
    s = reds[0] + reds[1] + reds[2] + reds[3];

    const float inv = 1.0f / s;
    float4 o;
    o.x = e0 * inv; o.y = e1 * inv; o.z = e2 * inv; o.w = e3 * inv;
    ((float4*)p)[t] = o;
}

extern "C" void kernel_launch(void* const* d_in, const int* in_sizes, int n_in,
                              void* d_out, int out_size, void* d_ws, size_t ws_size,
                              hipStream_t stream)
{
    (void)in_sizes; (void)n_in; (void)out_size; (void)ws_size;

    const int*   contexts = (const int*)d_in[0];
    const int*   replies  = (const int*)d_in[1];
    const float* ctx_emb  = (const float*)d_in[2];
    const float* ctx_Wih  = (const float*)d_in[3];
    const float* ctx_Whh  = (const float*)d_in[4];
    const float* ctx_bih  = (const float*)d_in[5];
    const float* ctx_bhh  = (const float*)d_in[6];
    const float* rep_emb  = (const float*)d_in[7];
    const float* rep_Wih  = (const float*)d_in[8];
    const float* rep_Whh  = (const float*)d_in[9];
    const float* rep_bih  = (const float*)d_in[10];
    const float* rep_bhh  = (const float*)d_in[11];
    float* out = (float*)d_out;

    // ---- workspace layout (fp16 elements) ----
    const size_t EMB_ELEMS = (size_t)VOCAB * KX;          // 6,400,000
    const size_t H_ELEMS   = (size_t)B_SZ * H_SZ;         // 524,288

    _Float16* base   = (_Float16*)d_ws;
    _Float16* embf_c = base;
    _Float16* embf_r = embf_c + EMB_ELEMS;
    _Float16* hB     = embf_r + EMB_ELEMS;     // pong [2][B][H]
    _Float16* hA     = hB + 2 * H_ELEMS;       // ping [2][B][H]
    unsigned int* bars  = (unsigned int*)(hA + 2 * H_ELEMS);  // 16*32 uints
    unsigned int* claim = bars + 16 * 32;                     // 8 uints

    // zero h0 (both GRUs, ping), barrier counters, and claim counters.
    hipMemsetAsync(hA, 0,
                   2 * H_ELEMS * sizeof(_Float16) +
                   (16 * 32 + 8) * sizeof(unsigned int), stream);

    // embedding tables fp32 -> fp16 (padded to 128)
    {
        const int total_emb = 2 * (int)EMB_ELEMS;
        prep_emb_kernel<<<(total_emb + 255) / 256, 256, 0, stream>>>(
            embf_c, ctx_emb, embf_r, rep_emb);
    }

    // one persistent kernel for all 128 GRU steps (both GRUs)
    GruArgs a;
    a.Whh[0] = ctx_Whh; a.Whh[1] = rep_Whh;
    a.Wih[0] = ctx_Wih; a.Wih[1] = rep_Wih;
    a.bih[0] = ctx_bih; a.bih[1] = rep_bih;
    a.bhh[0] = ctx_bhh; a.bhh[1] = rep_bhh;
    a.emb[0] = embf_c;  a.emb[1] = embf_r;
    a.idx[0] = contexts; a.idx[1] = replies;
    a.hA = hA; a.hB = hB; a.bars = bars; a.claim = claim;
    gru_persistent<<<dim3(256), dim3(512), 0, stream>>>(a);

    // final states: gru0 (ctx) at hA, gru1 (rep) at hA + B*H
    scores_kernel<<<dim3(B_SZ / 64, B_SZ / 64), 256, 0, stream>>>(hA, hA + H_ELEMS, out);
    softmax_kernel<<<B_SZ, 256, 0, stream>>>(out);
}

// Round 13
// 1005.766 us; speedup vs baseline: 1.2797x; 1.2797x over previous
//
#include <hip/hip_runtime.h>
#include <math.h>

// Problem constants
#define B_SZ   1024
#define H_SZ   512
#define E_SZ   100
#define L_SZ   128
#define KX     128          // embedding width padded 100 -> 128
#define VOCAB  50000

typedef _Float16 f16x8 __attribute__((ext_vector_type(8)));
typedef float    f32x4 __attribute__((ext_vector_type(4)));

#define MFMA16(a, b, c) __builtin_amdgcn_mfma_f32_16x16x32_f16((a), (b), (c), 0, 0, 0)

__device__ __forceinline__ float fast_sigmoid(float x) {
    return __builtin_amdgcn_rcpf(1.0f + __expf(-x));
}
__device__ __forceinline__ float fast_tanh(float x) {
    return 1.0f - 2.0f * __builtin_amdgcn_rcpf(1.0f + __expf(2.0f * x));
}

// ---------------------------------------------------------------------------
// Convert embedding tables to fp16, pad rows 100 -> 128.
// ---------------------------------------------------------------------------
__global__ __launch_bounds__(256) void prep_emb_kernel(
    _Float16* __restrict__ ef_c, const float* __restrict__ e_c,
    _Float16* __restrict__ ef_r, const float* __restrict__ e_r)
{
    const int PER = VOCAB * KX;                // 6,400,000
    int idx = blockIdx.x * 256 + threadIdx.x;
    if (idx >= 2 * PER) return;
    const int gru = idx >= PER;
    const int local = gru ? idx - PER : idx;
    const int v = local >> 7;                  // /128
    const int e = local & 127;
    const float* src = gru ? e_r : e_c;
    _Float16* dst = gru ? ef_r : ef_c;
    dst[local] = (_Float16)(e < E_SZ ? src[v * E_SZ + e] : 0.0f);
}

// ---------------------------------------------------------------------------
// Persistent GRU kernel: all 128 time steps in ONE launch.
//
// R23 = R16 VERBATIM (the session champion: gru 983-985us, total ~1006us).
// Restored after R22's L2-local barrier hang closed the last lever.
//
// Final structural accounting (13 rounds):
//   * Step time ~7.7us = 128-deep serial inter-CU chain: store-drain ->
//     LLC publish (~700cyc) -> LLC poll detect (~700cyc) -> h-burst from
//     L2/LLC -> ~5kcyc compute (x-part overlaps the wait) + 16-block tail
//     jitter. Arithmetic floor ~960-1020us == measured 985us.
//   * CLOSED levers (each with mechanism): LDS-read reduction (R15/R16/
//     R20/R21: CU LDS port 256B/clk, never critical); TLP/occupancy
//     (R18/R19: adding h-readers-per-row multiplies L2 traffic); sync
//     desync (R17/R18); barrier LLC->L2 (R12/R22: plain-atomic vs sc0
//     coherence points disagree -> hang).
//   * KEPT levers: conflict-free fragment-order LDS weights + 2 waves/SIMD
//     (R11, +270us); emb-gather software pipeline (R14, +50us); x-weight
//     register copy (R16, neutral-to-slightly-positive).
// ---------------------------------------------------------------------------
struct GruArgs {
    const float* Whh[2];
    const float* Wih[2];
    const float* bih[2];
    const float* bhh[2];
    const _Float16* emb[2];
    const int* idx[2];
    _Float16* hA;          // [2][1024][512] ping (h0 = 0, final h)
    _Float16* hB;          // [2][1024][512] pong
    unsigned int* bars;    // 16 groups, stride 32 uints (128B apart)
    unsigned int* claim;   // 8 per-XCD slot counters
};

__global__ __launch_bounds__(512, 2) void gru_persistent(GruArgs args)
{
    // ---- XCD discovery + role claim (once per block) ----
    __shared__ int role_s;
    if (threadIdx.x == 0) {
        unsigned xcd;
        asm volatile("s_getreg_b32 %0, hwreg(HW_REG_XCC_ID)" : "=s"(xcd));
        xcd &= 7u;
        unsigned slot = atomicAdd(&args.claim[xcd], 1u);   // device-scope
        role_s = (int)(xcd * 32u + slot);
    }
    __syncthreads();
    const int role = role_s;
    const int grp  = role >> 4;    // 0..15  (2 groups per XCD, XCD-local)
    const int ut   = role & 15;    // u-slice within group
    const int gru  = grp >> 3;
    const int mt   = grp & 7;

    const float* __restrict__ Whh = args.Whh[gru];
    const float* __restrict__ Wih = args.Wih[gru];
    const float* __restrict__ bih = args.bih[gru];
    const float* __restrict__ bhh = args.bhh[gru];
    const _Float16* __restrict__ embf = args.emb[gru];
    const int* __restrict__ idx = args.idx[gru];

    const int u0 = ut * 32;        // block's hidden-unit base (32 units)
    const int mB = mt * 128;       // block's batch-row base (128 rows)

    // Fragment-order weight store: [kc=20][g=3][u2=2][lane=64] x f16x8
    // = 7680 fragments x 16B = 122,880 B.
    __shared__ _Float16 Wl[7680 * 8];

    // ---- stage weights fp32 -> fp16 fragments (once) ----
    for (int f = threadIdx.x; f < 7680; f += 512) {
        const int ln  = f & 63;
        const int q   = f >> 6;          // 0..119
        const int kc  = q / 6;
        const int rem = q - kc * 6;
        const int g   = rem >> 1;
        const int u2  = rem & 1;
        const int row = g * H_SZ + u0 + u2 * 16 + (ln & 15);
        const int ks  = ln >> 4;
        _Float16 tmp[8];
        if (kc < 16) {
            const float* src = Whh + (size_t)row * H_SZ + kc * 32 + ks * 8;
#pragma unroll
            for (int j = 0; j < 8; ++j) tmp[j] = (_Float16)src[j];
        } else {
            const int e = (kc - 16) * 32 + ks * 8;
#pragma unroll
            for (int j = 0; j < 8; ++j)
                tmp[j] = (_Float16)((e + j < E_SZ) ? Wih[(size_t)row * E_SZ + e + j]
                                                   : 0.0f);
        }
        *(f16x8*)&Wl[(size_t)f * 8] = *(const f16x8*)tmp;
    }
    __syncthreads();

    const int lane = threadIdx.x & 63;
    const int wave = threadIdx.x >> 6;   // 0..7
    const int lr   = lane & 15;          // fragment row
    const int kseg = lane >> 4;          // 0..3
    const int mw   = mB + wave * 16;     // wave's 16-row batch base

    // per-lane fragment base: reads become base + const-offset
    const _Float16* Wbase = Wl + (size_t)lane * 8;
#define WFRAG(kc, g, u2) \
    (*(const f16x8*)(Wbase + (size_t)((((kc) * 3 + (g)) * 2 + (u2)) * 64) * 8))

    // ---- x-part weights -> registers where the compiler allows ----
    f16x8 xw[4][3][2];
#pragma unroll
    for (int xc = 0; xc < 4; ++xc)
#pragma unroll
        for (int g = 0; g < 3; ++g)
#pragma unroll
            for (int u2 = 0; u2 < 2; ++u2)
                xw[xc][g][u2] = WFRAG(16 + xc, g, u2);

    // bias preload: this thread's two u columns (u2 = 0,1)
    float bir[2], biz[2], binn[2], bhn[2];
    int ucol[2];
#pragma unroll
    for (int u2 = 0; u2 < 2; ++u2) {
        ucol[u2] = u0 + u2 * 16 + lr;
        const int u = ucol[u2];
        bir[u2]  = bih[u]             + bhh[u];
        biz[u2]  = bih[H_SZ + u]      + bhh[H_SZ + u];
        binn[u2] = bih[2 * H_SZ + u];
        bhn[u2]  = bhh[2 * H_SZ + u];
    }

    _Float16* hbuf0 = args.hA + (size_t)gru * B_SZ * H_SZ;
    _Float16* hbuf1 = args.hB + (size_t)gru * B_SZ * H_SZ;
    unsigned int* bar = args.bars + grp * 32;

    // h_prev at this thread's own output coordinates, carried in registers.
    float hreg[2][4] = {};   // [u2][r]

    // ---- emb software pipeline state (all compiler-managed loads) ----
    f16x8 er0, er1, er2, er3;
    int ivn;
    {
        const int iv_c = idx[(mw + lr) * L_SZ + (L_SZ - 1)];   // step 0
        const _Float16* e0 = embf + (size_t)iv_c * KX + kseg * 8;
        er0 = *(const f16x8*)(e0);
        er1 = *(const f16x8*)(e0 + 32);
        er2 = *(const f16x8*)(e0 + 64);
        er3 = *(const f16x8*)(e0 + 96);
        ivn = idx[(mw + lr) * L_SZ + (L_SZ - 2)];              // step 1
    }

#pragma unroll 1
    for (int step = 0; step < L_SZ; ++step) {
        const _Float16* __restrict__ hin = (step & 1) ? hbuf1 : hbuf0;
        _Float16* __restrict__ hout      = (step & 1) ? hbuf0 : hbuf1;

        f32x4 accr[2], accz[2], acchn[2], accin[2];
#pragma unroll
        for (int j = 0; j < 2; j++) {
            accr[j]  = (f32x4){0.f, 0.f, 0.f, 0.f};
            accz[j]  = (f32x4){0.f, 0.f, 0.f, 0.f};
            acchn[j] = (f32x4){0.f, 0.f, 0.f, 0.f};
            accin[j] = (f32x4){0.f, 0.f, 0.f, 0.f};
        }

        // ---- x-part: MFMAs on prefetched emb + register weights.
        //      ZERO LDS reads; issues immediately at step start. ----
#pragma unroll
        for (int xc = 0; xc < 4; ++xc) {
            const f16x8 ea = (xc == 0) ? er0 : (xc == 1) ? er1
                           : (xc == 2) ? er2 : er3;
#pragma unroll
            for (int u2 = 0; u2 < 2; ++u2) {
                accr[u2]  = MFMA16(ea, xw[xc][0][u2], accr[u2]);
                accz[u2]  = MFMA16(ea, xw[xc][1][u2], accz[u2]);
                accin[u2] = MFMA16(ea, xw[xc][2][u2], accin[u2]);
            }
        }

        // ---- wait for h(step): R11's PROVEN LLC barrier ----
        if (step > 0) {
            if (threadIdx.x == 0) {
                const unsigned tgt = 16u * (unsigned)step;
                while (__hip_atomic_load(bar, __ATOMIC_RELAXED,
                                         __HIP_MEMORY_SCOPE_AGENT) < tgt)
                    __builtin_amdgcn_s_sleep(1);
            }
            __syncthreads();
        }

        // ---- h-part A-slab: full K = 512 in ONE asm batch (R11-proven).
        // 16 pipelined sc0 loads (bypass L1, read local L2 where the
        // same-XCD producers' stores live), single INTERNAL vmcnt(0). ----
        const _Float16* hrow0 = hin + (mw + lr) * H_SZ + kseg * 8;
        f16x8 a0h[16];
        asm volatile(
            "global_load_dwordx4 %0,  %16, off sc0\n\t"
            "global_load_dwordx4 %1,  %16, off offset:64 sc0\n\t"
            "global_load_dwordx4 %2,  %16, off offset:128 sc0\n\t"
            "global_load_dwordx4 %3,  %16, off offset:192 sc0\n\t"
            "global_load_dwordx4 %4,  %16, off offset:256 sc0\n\t"
            "global_load_dwordx4 %5,  %16, off offset:320 sc0\n\t"
            "global_load_dwordx4 %6,  %16, off offset:384 sc0\n\t"
            "global_load_dwordx4 %7,  %16, off offset:448 sc0\n\t"
            "global_load_dwordx4 %8,  %16, off offset:512 sc0\n\t"
            "global_load_dwordx4 %9,  %16, off offset:576 sc0\n\t"
            "global_load_dwordx4 %10, %16, off offset:640 sc0\n\t"
            "global_load_dwordx4 %11, %16, off offset:704 sc0\n\t"
            "global_load_dwordx4 %12, %16, off offset:768 sc0\n\t"
            "global_load_dwordx4 %13, %16, off offset:832 sc0\n\t"
            "global_load_dwordx4 %14, %16, off offset:896 sc0\n\t"
            "global_load_dwordx4 %15, %16, off offset:960 sc0\n\t"
            "s_waitcnt vmcnt(0)"
            : "=&v"(a0h[0]),  "=&v"(a0h[1]),  "=&v"(a0h[2]),  "=&v"(a0h[3]),
              "=&v"(a0h[4]),  "=&v"(a0h[5]),  "=&v"(a0h[6]),  "=&v"(a0h[7]),
              "=&v"(a0h[8]),  "=&v"(a0h[9]),  "=&v"(a0h[10]), "=&v"(a0h[11]),
              "=&v"(a0h[12]), "=&v"(a0h[13]), "=&v"(a0h[14]), "=&v"(a0h[15])
            : "v"(hrow0)
            : "memory");

        // ---- emb prefetch for step+1 (compiler-managed; latency hides
        //      under the h-MFMA phase; publish syncthreads drains it) ----
        {
            const _Float16* erow = embf + (size_t)ivn * KX + kseg * 8;
            er0 = *(const f16x8*)(erow);
            er1 = *(const f16x8*)(erow + 32);
            er2 = *(const f16x8*)(erow + 64);
            er3 = *(const f16x8*)(erow + 96);
            int lc = L_SZ - 3 - step;          // lcol for step+2
            if (lc < 0) lc = 0;                // tail: valid junk, unused
            ivn = idx[(mw + lr) * L_SZ + lc];
        }

        // ---- h-part MFMAs: 16 kc x 6, fragment reads conflict-free ----
#pragma unroll
        for (int kc = 0; kc < 16; ++kc) {
#pragma unroll
            for (int u2 = 0; u2 < 2; ++u2) {
                f16x8 b0 = WFRAG(kc, 0, u2);
                f16x8 b1 = WFRAG(kc, 1, u2);
                f16x8 b2 = WFRAG(kc, 2, u2);
                accr[u2]  = MFMA16(a0h[kc], b0, accr[u2]);
                accz[u2]  = MFMA16(a0h[kc], b1, accz[u2]);
                acchn[u2] = MFMA16(a0h[kc], b2, acchn[u2]);
            }
        }

        // ---- epilogue: gates + state update; PLAIN stores -> local L2 ----
        // C/D layout: col = lane&15 (u), row = (lane>>4)*4 + reg (m)
#pragma unroll
        for (int u2 = 0; u2 < 2; ++u2) {
#pragma unroll
            for (int r = 0; r < 4; ++r) {
                const int m = mw + kseg * 4 + r;
                const float rg = fast_sigmoid(accr[u2][r] + bir[u2]);
                const float zg = fast_sigmoid(accz[u2][r] + biz[u2]);
                const float ng = fast_tanh(accin[u2][r] + binn[u2] +
                                           rg * (acchn[u2][r] + bhn[u2]));
                float nh = (1.0f - zg) * ng + zg * hreg[u2][r];
                nh = (float)(_Float16)nh;   // bit-match the stored fp16
                hreg[u2][r] = nh;
                hout[m * H_SZ + ucol[u2]] = (_Float16)nh;
            }
        }

        // ---- publish (RELAXED agent; stores drained to L2 by syncthreads) ----
        if (step + 1 < L_SZ) {
            __syncthreads();   // emits s_waitcnt vmcnt(0): stores visible in
                               // L2, emb prefetch fragments in regs
            if (threadIdx.x == 0) {
                __hip_atomic_fetch_add(bar, 1u, __ATOMIC_RELAXED,
                                       __HIP_MEMORY_SCOPE_AGENT);
            }
        }
    }
    // final h (step 127, odd) in hA as dirty local-L2 lines; the dispatch-end
    // release writes them back so the scores kernel sees them.
#undef WFRAG
}

// ---------------------------------------------------------------------------
// scores = hc @ hr^T (fp16 in, fp32 out), MFMA. Block 64x64, wave 32x32.
// ---------------------------------------------------------------------------
__global__ __launch_bounds__(256, 1) void scores_kernel(
    const _Float16* __restrict__ hc, const _Float16* __restrict__ hr,
    float* __restrict__ out)
{
    const int lane = threadIdx.x & 63;
    const int wave = threadIdx.x >> 6;
    const int lr   = lane & 15;
    const int kseg = lane >> 4;
    const int m0 = blockIdx.y * 64 + (wave >> 1) * 32;
    const int n0 = blockIdx.x * 64 + (wave & 1) * 32;

    f32x4 acc[2][2];
#pragma unroll
    for (int i = 0; i < 2; i++)
#pragma unroll
        for (int j = 0; j < 2; j++)
            acc[i][j] = (f32x4){0.f, 0.f, 0.f, 0.f};

#pragma unroll 2
    for (int kc = 0; kc < 16; kc++) {
        const int k0 = kc * 32 + kseg * 8;
        f16x8 a[2], b[2];
#pragma unroll
        for (int mt = 0; mt < 2; mt++)
            a[mt] = *(const f16x8*)(hc + (m0 + mt * 16 + lr) * H_SZ + k0);
#pragma unroll
        for (int nt = 0; nt < 2; nt++)
            b[nt] = *(const f16x8*)(hr + (n0 + nt * 16 + lr) * H_SZ + k0);
#pragma unroll
        for (int mt = 0; mt < 2; mt++)
#pragma unroll
            for (int nt = 0; nt < 2; nt++)
                acc[mt][nt] = MFMA16(a[mt], b[nt], acc[mt][nt]);
    }

#pragma unroll
    for (int mt = 0; mt < 2; mt++)
#pragma unroll
        for (int nt = 0; nt < 2; nt++)
#pragma unroll
            for (int r = 0; r < 4; r++) {
                const int m = m0 + mt * 16 + kseg * 4 + r;
                const int n = n0 + nt * 16 + lr;
                out[m * B_SZ + n] = acc[mt][nt][r];
            }
}

// In-place row softmax on [1024, 1024]; one block per row.
__global__ __launch_bounds__(256) void softmax_kernel(float* __restrict__ out)
{
    const int row = blockIdx.x;
    float* p = out + (size_t)row * B_SZ;
    const int t = threadIdx.x;
    const int wave = t >> 6;
    const int lane = t & 63;

    float4 v = ((const float4*)p)[t];
    float m = fmaxf(fmaxf(v.x, v.y), fmaxf(v.z, v.w));
#pragma unroll
    for (int off = 32; off >= 1; off >>= 1)
        m = fmaxf(m, __shfl_xor(m, off, 64));

    __shared__ float redm[4];
    if (lane == 0) redm[wave] = m;
    __syncthreads();
    m = fmaxf(fmaxf(redm[0], redm[1]), fmaxf(redm[2], redm[3]));

    const float e0 = __expf(v.x - m);
    const float e1 = __expf(v.y - m);
    const float e2 = __expf(v.z - m);
    const float e3 = __expf(v.w - m);
    float s = e0 + e1 + e2 + e3;
#pragma unroll
    for (int off = 32; off >= 1; off >>= 1)
        s += __shfl_xor(s, off, 64);

    __shared__ float reds[4];
    if (lane == 0) reds[wave] = s;
    __syncthreads();
    s = reds[0] + reds[1] + reds[2] + reds[3];

    const float inv = 1.0f / s;
    float4 o;
    o.x = e0 * inv; o.y = e1 * inv; o.z = e2 * inv; o.w = e3 * inv;
    ((float4*)p)[t] = o;
}

extern "C" void kernel_launch(void* const* d_in, const int* in_sizes, int n_in,
                              void* d_out, int out_size, void* d_ws, size_t ws_size,
                              hipStream_t stream)
{
    (void)in_sizes; (void)n_in; (void)out_size; (void)ws_size;

    const int*   contexts = (const int*)d_in[0];
    const int*   replies  = (const int*)d_in[1];
    const float* ctx_emb  = (const float*)d_in[2];
    const float* ctx_Wih  = (const float*)d_in[3];
    const float* ctx_Whh  = (const float*)d_in[4];
    const float* ctx_bih  = (const float*)d_in[5];
    const float* ctx_bhh  = (const float*)d_in[6];
    const float* rep_emb  = (const float*)d_in[7];
    const float* rep_Wih  = (const float*)d_in[8];
    const float* rep_Whh  = (const float*)d_in[9];
    const float* rep_bih  = (const float*)d_in[10];
    const float* rep_bhh  = (const float*)d_in[11];
    float* out = (float*)d_out;

    // ---- workspace layout (fp16 elements) ----
    const size_t EMB_ELEMS = (size_t)VOCAB * KX;          // 6,400,000
    const size_t H_ELEMS   = (size_t)B_SZ * H_SZ;         // 524,288

    _Float16* base   = (_Float16*)d_ws;
    _Float16* embf_c = base;
    _Float16* embf_r = embf_c + EMB_ELEMS;
    _Float16* hB     = embf_r + EMB_ELEMS;     // pong [2][B][H]
    _Float16* hA     = hB + 2 * H_ELEMS;       // ping [2][B][H]
    unsigned int* bars  = (unsigned int*)(hA + 2 * H_ELEMS);  // 16*32 uints
    unsigned int* claim = bars + 16 * 32;                     // 8 uints

    // zero h0 (both GRUs, ping), barrier counters, and claim counters.
    hipMemsetAsync(hA, 0,
                   2 * H_ELEMS * sizeof(_Float16) +
                   (16 * 32 + 8) * sizeof(unsigned int), stream);

    // embedding tables fp32 -> fp16 (padded to 128)
    {
        const int total_emb = 2 * (int)EMB_ELEMS;
        prep_emb_kernel<<<(total_emb + 255) / 256, 256, 0, stream>>>(
            embf_c, ctx_emb, embf_r, rep_emb);
    }

    // one persistent kernel for all 128 GRU steps (both GRUs)
    GruArgs a;
    a.Whh[0] = ctx_Whh; a.Whh[1] = rep_Whh;
    a.Wih[0] = ctx_Wih; a.Wih[1] = rep_Wih;
    a.bih[0] = ctx_bih; a.bih[1] = rep_bih;
    a.bhh[0] = ctx_bhh; a.bhh[1] = rep_bhh;
    a.emb[0] = embf_c;  a.emb[1] = embf_r;
    a.idx[0] = contexts; a.idx[1] = replies;
    a.hA = hA; a.hB = hB; a.bars = bars; a.claim = claim;
    gru_persistent<<<dim3(256), dim3(512), 0, stream>>>(a);

    // final states: gru0 (ctx) at hA, gru1 (rep) at hA + B*H
    scores_kernel<<<dim3(B_SZ / 64, B_SZ / 64), 256, 0, stream>>>(hA, hA + H_ELEMS, out);
    softmax_kernel<<<B_SZ, 256, 0, stream>>>(out);
}